// Round 9
// baseline (195.276 us; speedup 1.0000x reference)
//
#include <hip/hip_runtime.h>
#include <hip/hip_bf16.h>
#include <hip/hip_fp16.h>

#define F 32
#define S 16

typedef short v8s __attribute__((ext_vector_type(8)));
typedef _Float16 v8h __attribute__((ext_vector_type(8)));
typedef float v4f __attribute__((ext_vector_type(4)));

__device__ __forceinline__ float bf_lo(unsigned u) { return __uint_as_float(u << 16); }
__device__ __forceinline__ float bf_hi(unsigned u) { return __uint_as_float(u & 0xffff0000u); }
__device__ __forceinline__ unsigned short f2bf(float f) {
    __hip_bfloat16 h = __float2bfloat16(f);  // RNE
    return *(unsigned short*)&h;
}
__device__ __forceinline__ unsigned short f2h(float f) {
    __half h = __float2half(f);              // RNE
    return *(unsigned short*)&h;
}
__device__ __forceinline__ unsigned pack2(float a, float b) {
    __hip_bfloat162 h2 = __float22bfloat162_rn(make_float2(a, b));  // v_cvt_pk_bf16_f32
    return *(unsigned*)&h2;
}
__device__ __forceinline__ unsigned pack2h(float a, float b) {
    __half2 h2 = __floats2half2_rn(a, b);    // packed f32->f16
    return *(unsigned*)&h2;
}
static inline size_t align256(size_t b) { return (b + 255) & ~(size_t)255; }

// ---------------------------------------------------------------------------
// prep: weight repack [0,144) + dst histogram [144,144+eB) + x->f16 [rest).
// ---------------------------------------------------------------------------
__global__ __launch_bounds__(256) void prep_kernel(
    const float* __restrict__ w1, const float* __restrict__ b1, const float* __restrict__ r1,
    const float* __restrict__ w2, const float* __restrict__ b2, const float* __restrict__ r2,
    unsigned short* __restrict__ Wf1, unsigned short* __restrict__ Wf2,
    unsigned short* __restrict__ Rt1, unsigned short* __restrict__ Rt2,
    const int* __restrict__ dst, int* __restrict__ cnt,
    const float* __restrict__ x, unsigned short* __restrict__ x16,
    int N, int E, int eB)
{
    const int PER = 34 * 512 + 32 * 32;
    if (blockIdx.x < 144) {
        int tid = blockIdx.x * blockDim.x + threadIdx.x;
        if (tid >= 2 * PER) return;
        const int layer = tid / PER;
        const int rem   = tid % PER;
        const float* w = layer ? w2 : w1;
        const float* b = layer ? b2 : b1;
        const float* r = layer ? r2 : r1;
        if (rem < 34 * 512) {
            const int fi   = rem >> 9;
            const int rr   = rem & 511;
            const int lane = rr >> 3;
            const int j    = rr & 7;
            const int half = fi & 1;
            const int ck   = fi >> 1;
            const int o    = (half << 4) | (lane & 15);
            const int k    = ck * 32 + (lane >> 4) * 8 + j;
            const int s    = k >> 5, f = k & 31;
            const float v  = (s < S) ? w[s * (F * F) + f * F + o] : b[f * F + o];
            (layer ? Wf2 : Wf1)[rem] = f2h(v);   // F16
        } else {
            const int q = rem - 34 * 512;
            const int o = q >> 5, f = q & 31;
            (layer ? Rt2 : Rt1)[o * F + f] = f2bf(r[f * F + o]);
        }
    } else if (blockIdx.x < 144 + eB) {
        const int e = (blockIdx.x - 144) * blockDim.x + threadIdx.x;
        if (e < E) atomicAdd(&cnt[dst[e]], 1);
    } else {
        // x -> f16 (8 floats per thread)
        const int idx = (blockIdx.x - 144 - eB) * 256 + threadIdx.x;
        if (idx < N * 4) {
            const float4* p = (const float4*)(x + (size_t)idx * 8);
            float4 a = p[0], b = p[1];
            uint4 o;
            o.x = pack2h(a.x, a.y); o.y = pack2h(a.z, a.w);
            o.z = pack2h(b.x, b.y); o.w = pack2h(b.z, b.w);
            *(uint4*)(x16 + (size_t)idx * 8) = o;
        }
    }
}

// ---------------------------------------------------------------------------
// scan_partial: per-block sums.
// ---------------------------------------------------------------------------
__global__ __launch_bounds__(256) void scan_partial(
    const int* __restrict__ cnt, int* __restrict__ partial, int N)
{
    const int i = blockIdx.x * 256 + threadIdx.x;
    int v = (i < N) ? cnt[i] : 0;
    #pragma unroll
    for (int off = 32; off > 0; off >>= 1) v += __shfl_down(v, off, 64);
    __shared__ int wsum[4];
    const int wave = threadIdx.x >> 6, lane = threadIdx.x & 63;
    if (lane == 0) wsum[wave] = v;
    __syncthreads();
    if (threadIdx.x == 0)
        partial[blockIdx.x] = wsum[0] + wsum[1] + wsum[2] + wsum[3];
}

// ---------------------------------------------------------------------------
// scan_final: computes its own block-prefix from raw per-block sums.
// ---------------------------------------------------------------------------
__global__ __launch_bounds__(256) void scan_final(
    const int* __restrict__ cnt, const int* __restrict__ partial,
    int* __restrict__ cursor, int* __restrict__ rowptr, int N)
{
    const int tid = threadIdx.x;
    __shared__ int pacc[256];
    int pre = 0;
    for (int j = tid; j < blockIdx.x; j += 256) pre += partial[j];
    pacc[tid] = pre;
    __syncthreads();
    #pragma unroll
    for (int off = 128; off > 0; off >>= 1) {
        if (tid < off) pacc[tid] += pacc[tid + off];
        __syncthreads();
    }
    const int blockPre = pacc[0];

    const int i = blockIdx.x * 256 + tid;
    const int v0 = (i < N) ? cnt[i] : 0;
    int v = v0;
    const int wave = tid >> 6, lane = tid & 63;
    #pragma unroll
    for (int off = 1; off < 64; off <<= 1) {
        int u = __shfl_up(v, off, 64);
        if (lane >= off) v += u;
    }
    __shared__ int wsum[4];
    if (lane == 63) wsum[wave] = v;
    __syncthreads();
    int woff = 0;
    for (int ww = 0; ww < 4; ++ww) woff += (ww < wave) ? wsum[ww] : 0;
    if (i < N) {
        const int excl = blockPre + woff + (v - v0);
        cursor[i] = excl;
        rowptr[i] = excl;
    }
}

__global__ __launch_bounds__(256) void scatter_kernel(
    const int* __restrict__ dst, int* __restrict__ cursor,
    int* __restrict__ perm, int E)
{
    int e = blockIdx.x * blockDim.x + threadIdx.x;
    if (e < E) {
        int p = atomicAdd(&cursor[dst[e]], 1);
        perm[p] = e;
    }
}

// ---------------------------------------------------------------------------
// edge_msg: 512-thread blocks (8 waves) share the 34KB weight stage ->
// 4 blocks/CU x 8 waves = 32 waves/CU (full occupancy; was 16) to hide the
// src->x16 gather latency chain. F16 fragments via v_pk_mul_f16.
// ---------------------------------------------------------------------------
__global__ __launch_bounds__(512) void edge_msg(
    const unsigned short* __restrict__ x16,
    const float* __restrict__ ef,
    const int* __restrict__ src,
    const unsigned short* __restrict__ Wf,
    unsigned short* __restrict__ msg,
    int E)
{
    __shared__ v8h Wl[34 * 64];
    const int tid  = threadIdx.x;
    const int w    = tid >> 6;           // 0..7
    const int lane = tid & 63;
    const int lid  = lane & 15;
    const int quad = lane >> 4;

    {
        const uint4* s = (const uint4*)Wf;
        uint4* d = (uint4*)Wl;
        #pragma unroll
        for (int i = 0; i < 5; ++i) {
            const int idx = tid + 512 * i;
            if (idx < 2176) d[idx] = s[idx];
        }
    }
    __syncthreads();

    const int nTiles = (E + 15) >> 4;
    const int stride = gridDim.x * 8;
    int tile = blockIdx.x * 8 + w;
    if (tile >= nTiles) return;

    int  slot = tile * 16 + lid;
    bool live = (slot < E);
    int  s0   = live ? slot : 0;
    int  sn   = src[s0];
    v8h xh = *(const v8h*)(x16 + (size_t)sn * F + quad * 8);
    const float4* efv = (const float4*)(ef + (size_t)s0 * S);
    float4 c0 = efv[0], c1 = efv[1], c2 = efv[2], c3 = efv[3];

    while (true) {
        const int nextTile = tile + stride;
        v8h nxh;
        float4 nc0, nc1, nc2, nc3;
        bool nlive = false;
        if (nextTile < nTiles) {
            const int  ns_  = nextTile * 16 + lid;
            nlive = (ns_ < E);
            const int  ns0_ = nlive ? ns_ : 0;
            const int  nsn  = src[ns0_];
            nxh = *(const v8h*)(x16 + (size_t)nsn * F + quad * 8);
            const float4* nefv = (const float4*)(ef + (size_t)ns0_ * S);
            nc0 = nefv[0]; nc1 = nefv[1]; nc2 = nefv[2]; nc3 = nefv[3];
        }

        const float cs[S] = {c0.x, c0.y, c0.z, c0.w, c1.x, c1.y, c1.z, c1.w,
                             c2.x, c2.y, c2.z, c2.w, c3.x, c3.y, c3.z, c3.w};

        union { v8h h8; __half2 h2[4]; } xu;
        xu.h8 = xh;

        v4f acc0 = {0.f, 0.f, 0.f, 0.f};
        v4f acc1 = {0.f, 0.f, 0.f, 0.f};

        #pragma unroll
        for (int ck = 0; ck < S; ++ck) {
            const __half2 cc = __floats2half2_rn(cs[ck], cs[ck]);
            union { v8h h8; __half2 h2[4]; } fr;
            fr.h2[0] = __hmul2(cc, xu.h2[0]);
            fr.h2[1] = __hmul2(cc, xu.h2[1]);
            fr.h2[2] = __hmul2(cc, xu.h2[2]);
            fr.h2[3] = __hmul2(cc, xu.h2[3]);
            acc0 = __builtin_amdgcn_mfma_f32_16x16x32_f16(Wl[(2 * ck) * 64 + lane],     fr.h8, acc0, 0, 0, 0);
            acc1 = __builtin_amdgcn_mfma_f32_16x16x32_f16(Wl[(2 * ck + 1) * 64 + lane], fr.h8, acc1, 0, 0, 0);
        }
        acc0 = __builtin_amdgcn_mfma_f32_16x16x32_f16(Wl[32 * 64 + lane], xu.h8, acc0, 0, 0, 0);
        acc1 = __builtin_amdgcn_mfma_f32_16x16x32_f16(Wl[33 * 64 + lane], xu.h8, acc1, 0, 0, 0);

        if (live) {
            unsigned short* mp = msg + (size_t)slot * 32;
            uint2 p0, p1;
            p0.x = pack2(acc0[0], acc0[1]);
            p0.y = pack2(acc0[2], acc0[3]);
            p1.x = pack2(acc1[0], acc1[1]);
            p1.y = pack2(acc1[2], acc1[3]);
            *(uint2*)(mp + quad * 4)      = p0;
            *(uint2*)(mp + 16 + quad * 4) = p1;
        }

        if (nextTile >= nTiles) break;
        tile = nextTile;
        slot = tile * 16 + lid;
        live = nlive;
        xh = nxh;
        c0 = nc0; c1 = nc1; c2 = nc2; c3 = nc3;
    }
}

// ---------------------------------------------------------------------------
// rootsum (layer 1): reads f32 x for root term; writes h ONLY as F16.
// ---------------------------------------------------------------------------
__global__ __launch_bounds__(256) void rootsum(
    const float* __restrict__ in,
    const unsigned short* __restrict__ msg,
    const int* __restrict__ rowptr,
    const int* __restrict__ cnt,
    const int* __restrict__ perm,
    const unsigned short* __restrict__ Rt,
    const float* __restrict__ bias,
    unsigned short* __restrict__ h16,
    int N)
{
    __shared__ float acc[64 * 33];
    __shared__ unsigned short As[64 * F];
    const int tid  = threadIdx.x;
    const int n0   = blockIdx.x * 64;
    const int w    = tid >> 6;
    const int lane = tid & 63;
    const int lid  = lane & 15;
    const int quad = lane >> 4;

    {
        const int nl = tid >> 2;
        const int kq = tid & 3;
        int n = n0 + nl; if (n > N - 1) n = N - 1;
        const float4* xp = (const float4*)(in + (size_t)n * F + kq * 8);
        float4 v0 = xp[0], v1 = xp[1];
        uint4 pk;
        pk.x = pack2(v0.x, v0.y);
        pk.y = pack2(v0.z, v0.w);
        pk.z = pack2(v1.x, v1.y);
        pk.w = pack2(v1.z, v1.w);
        const int slot = ((nl >> 4) * 4 + kq) * 16 + (nl & 15);
        *(uint4*)(As + slot * 8) = pk;
    }

    {
        const int nl = tid >> 2;
        const int oq = tid & 3;
        const int n  = n0 + nl;
        float a[8];
        #pragma unroll
        for (int j = 0; j < 8; ++j) a[j] = 0.f;
        if (n < N) {
            const int k0 = rowptr[n];
            const int k1 = k0 + cnt[n];
            for (int k = k0; k < k1; ++k) {
                const int e = perm[k];
                const uint4 q = *(const uint4*)(msg + (size_t)e * 32 + oq * 8);
                a[0] += bf_lo(q.x); a[1] += bf_hi(q.x);
                a[2] += bf_lo(q.y); a[3] += bf_hi(q.y);
                a[4] += bf_lo(q.z); a[5] += bf_hi(q.z);
                a[6] += bf_lo(q.w); a[7] += bf_hi(q.w);
            }
        }
        float* ap = acc + nl * 33 + oq * 8;
        #pragma unroll
        for (int j = 0; j < 8; ++j) ap[j] = a[j];
    }
    __syncthreads();

    const int jt  = w & 1;
    const int ns0 = (w >> 1) * 2;
    const v8s rf = *(const v8s*)(Rt + (size_t)(jt * 16 + lid) * F + quad * 8);
    const int o0 = jt * 16 + quad * 4;
    const float4 bs = *(const float4*)(bias + o0);

    #pragma unroll
    for (int i = 0; i < 2; ++i) {
        const int ns = ns0 + i;
        const v8s af = *(const v8s*)(As + (((ns * 4 + quad) * 16) + lid) * 8);
        v4f d = {0.f, 0.f, 0.f, 0.f};
        d = __builtin_amdgcn_mfma_f32_16x16x32_bf16(rf, af, d, 0, 0, 0);
        const int n = n0 + ns * 16 + lid;
        if (n < N) {
            const float* ap = acc + (ns * 16 + lid) * 33 + o0;
            float4 hv;
            hv.x = fmaxf(d[0] + ap[0] + bs.x, 0.f);
            hv.y = fmaxf(d[1] + ap[1] + bs.y, 0.f);
            hv.z = fmaxf(d[2] + ap[2] + bs.z, 0.f);
            hv.w = fmaxf(d[3] + ap[3] + bs.w, 0.f);
            uint2 hp;
            hp.x = pack2h(hv.x, hv.y);
            hp.y = pack2h(hv.z, hv.w);
            *(uint2*)(h16 + (size_t)n * F + o0) = hp;
        }
    }
}

// ---------------------------------------------------------------------------
// rootsum_pool (layer 2): stages root term from F16 h; per-block pooled
// partials to bs (no device-scope fence — R7 lesson).
// ---------------------------------------------------------------------------
__global__ __launch_bounds__(256) void rootsum_pool(
    const unsigned short* __restrict__ in16,
    const unsigned short* __restrict__ msg,
    const int* __restrict__ rowptr,
    const int* __restrict__ cnt,
    const int* __restrict__ perm,
    const unsigned short* __restrict__ Rt,
    const float* __restrict__ bias,
    float* __restrict__ bs,
    int N)
{
    __shared__ float acc[64 * 33];
    __shared__ unsigned short As[64 * F];
    __shared__ float poolbuf[4][16];
    const int tid  = threadIdx.x;
    const int n0   = blockIdx.x * 64;
    const int w    = tid >> 6;
    const int lane = tid & 63;
    const int lid  = lane & 15;
    const int quad = lane >> 4;

    {
        const int nl = tid >> 2;
        const int kq = tid & 3;
        int n = n0 + nl; if (n > N - 1) n = N - 1;
        const uint4 hv4 = *(const uint4*)(in16 + (size_t)n * F + kq * 8);
        const __half2* hh = (const __half2*)&hv4;
        float2 f0 = __half22float2(hh[0]);
        float2 f1 = __half22float2(hh[1]);
        float2 f2 = __half22float2(hh[2]);
        float2 f3 = __half22float2(hh[3]);
        uint4 pk;
        pk.x = pack2(f0.x, f0.y);
        pk.y = pack2(f1.x, f1.y);
        pk.z = pack2(f2.x, f2.y);
        pk.w = pack2(f3.x, f3.y);
        const int slot = ((nl >> 4) * 4 + kq) * 16 + (nl & 15);
        *(uint4*)(As + slot * 8) = pk;
    }

    {
        const int nl = tid >> 2;
        const int oq = tid & 3;
        const int n  = n0 + nl;
        float a[8];
        #pragma unroll
        for (int j = 0; j < 8; ++j) a[j] = 0.f;
        if (n < N) {
            const int k0 = rowptr[n];
            const int k1 = k0 + cnt[n];
            for (int k = k0; k < k1; ++k) {
                const int e = perm[k];
                const uint4 q = *(const uint4*)(msg + (size_t)e * 32 + oq * 8);
                a[0] += bf_lo(q.x); a[1] += bf_hi(q.x);
                a[2] += bf_lo(q.y); a[3] += bf_hi(q.y);
                a[4] += bf_lo(q.z); a[5] += bf_hi(q.z);
                a[6] += bf_lo(q.w); a[7] += bf_hi(q.w);
            }
        }
        float* ap = acc + nl * 33 + oq * 8;
        #pragma unroll
        for (int j = 0; j < 8; ++j) ap[j] = a[j];
    }
    __syncthreads();

    const int jt  = w & 1;
    const int ns0 = (w >> 1) * 2;
    const v8s rf = *(const v8s*)(Rt + (size_t)(jt * 16 + lid) * F + quad * 8);
    const int o0 = jt * 16 + quad * 4;
    const float4 bs4 = *(const float4*)(bias + o0);

    float psum[4] = {0.f, 0.f, 0.f, 0.f};

    #pragma unroll
    for (int i = 0; i < 2; ++i) {
        const int ns = ns0 + i;
        const v8s af = *(const v8s*)(As + (((ns * 4 + quad) * 16) + lid) * 8);
        v4f d = {0.f, 0.f, 0.f, 0.f};
        d = __builtin_amdgcn_mfma_f32_16x16x32_bf16(rf, af, d, 0, 0, 0);
        const int n = n0 + ns * 16 + lid;
        if (n < N) {
            const float* ap = acc + (ns * 16 + lid) * 33 + o0;
            psum[0] += fmaxf(d[0] + ap[0] + bs4.x, 0.f);
            psum[1] += fmaxf(d[1] + ap[1] + bs4.y, 0.f);
            psum[2] += fmaxf(d[2] + ap[2] + bs4.z, 0.f);
            psum[3] += fmaxf(d[3] + ap[3] + bs4.w, 0.f);
        }
    }

    #pragma unroll
    for (int m = 1; m < 16; m <<= 1) {
        psum[0] += __shfl_xor(psum[0], m, 64);
        psum[1] += __shfl_xor(psum[1], m, 64);
        psum[2] += __shfl_xor(psum[2], m, 64);
        psum[3] += __shfl_xor(psum[3], m, 64);
    }
    if (lid == 0) {
        #pragma unroll
        for (int j = 0; j < 4; ++j) poolbuf[w][quad * 4 + j] = psum[j];
    }
    __syncthreads();
    if (tid < 32) {
        const int jt2 = tid >> 4, idx = tid & 15;
        bs[(size_t)blockIdx.x * 32 + tid] = poolbuf[jt2][idx] + poolbuf[jt2 + 2][idx];
    }
}

// ---------------------------------------------------------------------------
// final_fused: reduce per-block pooled partials + dense head in one launch.
// ---------------------------------------------------------------------------
__global__ __launch_bounds__(256) void final_fused(
    const float* __restrict__ bs, int nb,
    const float* __restrict__ dw, const float* __restrict__ db,
    float* __restrict__ out)
{
    const int ch = threadIdx.x & 31, g = threadIdx.x >> 5;  // 8 row-groups
    float s = 0.f;
    for (int b = g; b < nb; b += 8) s += bs[(size_t)b * 32 + ch];
    __shared__ float red[256];
    red[threadIdx.x] = s;
    __syncthreads();
    if (threadIdx.x < 128) red[threadIdx.x] += red[threadIdx.x + 128];
    __syncthreads();
    if (threadIdx.x < 64) red[threadIdx.x] += red[threadIdx.x + 64];
    __syncthreads();
    if (threadIdx.x < 32) red[threadIdx.x] = (red[threadIdx.x] + red[threadIdx.x + 32]) * dw[threadIdx.x];
    __syncthreads();
    if (threadIdx.x == 0) {
        float t = 0.f;
        #pragma unroll
        for (int i = 0; i < 32; ++i) t += red[i];
        out[0] = t + db[0];
    }
}

// ---------------------------------------------------------------------------
// pool/final kernels retained for the fallback path.
// ---------------------------------------------------------------------------
__global__ __launch_bounds__(256) void pool_kernel(
    const float* __restrict__ h, float* __restrict__ pooled, int N)
{
    const int c = threadIdx.x & (F - 1);
    float p = 0.0f;
    for (int n = blockIdx.x * 8 + (threadIdx.x >> 5); n < N; n += gridDim.x * 8)
        p += h[(size_t)n * F + c];
    __shared__ float red[256];
    red[threadIdx.x] = p;
    __syncthreads();
    for (int off = 128; off >= F; off >>= 1) {
        if (threadIdx.x < off) red[threadIdx.x] += red[threadIdx.x + off];
        __syncthreads();
    }
    if (threadIdx.x < F) atomicAdd(&pooled[threadIdx.x], red[threadIdx.x]);
}

__global__ void final_kernel(
    const float* __restrict__ pooled, const float* __restrict__ dw,
    const float* __restrict__ db, float* __restrict__ out)
{
    const int o = threadIdx.x;
    float v = (o < F) ? pooled[o] * dw[o] : 0.0f;
    #pragma unroll
    for (int off = 32; off > 0; off >>= 1) v += __shfl_down(v, off, 64);
    if (o == 0) out[0] = v + db[0];
}

// ---------------------------------------------------------------------------
// Last-resort fallback (tiny ws): round-1 implementation.
// ---------------------------------------------------------------------------
__global__ __launch_bounds__(256, 2) void ecc_edge_slow(
    const float* __restrict__ x, const float* __restrict__ ef,
    const int* __restrict__ src, const int* __restrict__ dst,
    const float* __restrict__ W, const float* __restrict__ B,
    float* __restrict__ agg, int E)
{
    const int tid = blockIdx.x * blockDim.x + threadIdx.x;
    const bool live = (tid < E);
    const int e = live ? tid : (E - 1);
    const int sn = src[e], dn = dst[e];
    float xr[F];
    const float4* xp = (const float4*)(x + (size_t)sn * F);
    #pragma unroll
    for (int i = 0; i < F / 4; ++i) {
        float4 v = xp[i];
        xr[4*i+0] = v.x; xr[4*i+1] = v.y; xr[4*i+2] = v.z; xr[4*i+3] = v.w;
    }
    float acc[F];
    #pragma unroll
    for (int o = 0; o < F; ++o) acc[o] = 0.0f;
    const float* erow = ef + (size_t)e * S;
    for (int s = 0; s < S; ++s) {
        const float es = erow[s];
        const float* Ws = W + s * (F * F);
        #pragma unroll
        for (int f = 0; f < F; ++f) {
            const float z = es * xr[f];
            #pragma unroll
            for (int o = 0; o < F; ++o) acc[o] = fmaf(z, Ws[f * F + o], acc[o]);
        }
    }
    #pragma unroll
    for (int f = 0; f < F; ++f) {
        const float xf = xr[f];
        #pragma unroll
        for (int o = 0; o < F; ++o) acc[o] = fmaf(xf, B[f * F + o], acc[o]);
    }
    if (live) {
        float* ap = agg + (size_t)dn * F;
        #pragma unroll
        for (int o = 0; o < F; ++o) atomicAdd(ap + o, acc[o]);
    }
}

__global__ __launch_bounds__(256) void ecc_node_slow(
    const float* __restrict__ xin, const float* __restrict__ root,
    const float* __restrict__ bias, float* __restrict__ h, int N)
{
    int t = blockIdx.x * blockDim.x + threadIdx.x;
    if (t >= N * F) return;
    const int n = t >> 5, o = t & (F - 1);
    const float* xrow = xin + (size_t)n * F;
    float v = h[t] + bias[o];
    #pragma unroll
    for (int f = 0; f < F; ++f) v = fmaf(xrow[f], root[f * F + o], v);
    h[t] = fmaxf(v, 0.0f);
}

// ---------------------------------------------------------------------------
extern "C" void kernel_launch(void* const* d_in, const int* in_sizes, int n_in,
                              void* d_out, int out_size, void* d_ws, size_t ws_size,
                              hipStream_t stream) {
    const float* x      = (const float*)d_in[0];
    const float* efeat  = (const float*)d_in[1];
    const int*   src    = (const int*)d_in[2];
    const int*   dst    = (const int*)d_in[3];
    const float* fgn_w1 = (const float*)d_in[4];
    const float* fgn_b1 = (const float*)d_in[5];
    const float* root1  = (const float*)d_in[6];
    const float* bias1  = (const float*)d_in[7];
    const float* fgn_w2 = (const float*)d_in[8];
    const float* fgn_b2 = (const float*)d_in[9];
    const float* root2  = (const float*)d_in[10];
    const float* bias2  = (const float*)d_in[11];
    const float* dense_w = (const float*)d_in[12];
    const float* dense_b = (const float*)d_in[13];

    const int N = in_sizes[0] / F;
    const int E = in_sizes[2];

    const int gridP    = (N + 255) / 256;
    const int rsBlocks = (N + 63) / 64;

    const size_t pooledB = 256;
    const size_t cntB    = align256((size_t)N * 4);
    const size_t rowB    = align256((size_t)N * 4);
    const size_t curB    = align256((size_t)N * 4);
    const size_t partB   = align256((size_t)gridP * 4);
    const size_t permB   = align256((size_t)E * 4);
    const size_t efsB    = align256((size_t)E * S * 4);
    const size_t srcsB   = align256((size_t)E * 4);
    const size_t msgB    = align256((size_t)E * 32 * 2);
    const size_t hB      = (size_t)N * F * 4;
    const size_t wfB     = align256((size_t)34 * 512 * 2);
    const size_t rtB     = align256((size_t)32 * 32 * 2);
    const size_t x16B    = align256((size_t)N * F * 2);

    const size_t offCnt  = pooledB;
    const size_t offRow  = offCnt + cntB;
    const size_t offCur  = offRow + rowB;
    const size_t offPart = offCur + curB;
    const size_t offPerm = offPart + partB;
    const size_t offEfs  = offPerm + permB;
    const size_t offSrcs = offEfs + efsB;
    const size_t offMsg  = offSrcs + srcsB;
    const size_t offH1   = offMsg + msgB;
    const size_t offH2   = offH1 + hB;
    const size_t offW1   = offH2 + hB;
    const size_t offW2   = offW1 + wfB;
    const size_t offR1   = offW2 + wfB;
    const size_t offR2   = offR1 + rtB;
    const size_t need    = offR2 + rtB;

    const int eB         = (E + 255) / 256;
    const int nodeBlocks = (N * F + 255) / 256;

    if (ws_size >= need && efsB >= 2 * x16B) {
        int* cnt     = (int*)((char*)d_ws + offCnt);
        int* rowptr  = (int*)((char*)d_ws + offRow);
        int* cursor  = (int*)((char*)d_ws + offCur);
        int* partial = (int*)((char*)d_ws + offPart);
        int* perm    = (int*)((char*)d_ws + offPerm);
        unsigned short* x16 = (unsigned short*)((char*)d_ws + offEfs);
        unsigned short* h16 = (unsigned short*)((char*)d_ws + offEfs + x16B);
        unsigned short* msg = (unsigned short*)((char*)d_ws + offMsg);
        float* bsum  = (float*)((char*)d_ws + offH2);
        unsigned short* Wf1 = (unsigned short*)((char*)d_ws + offW1);
        unsigned short* Wf2 = (unsigned short*)((char*)d_ws + offW2);
        unsigned short* Rt1 = (unsigned short*)((char*)d_ws + offR1);
        unsigned short* Rt2 = (unsigned short*)((char*)d_ws + offR2);

        hipMemsetAsync(d_ws, 0, pooledB + cntB, stream);

        // weight repack + dst histogram + x->f16 in one launch
        const int xcB = (N * 4 + 255) / 256;
        prep_kernel<<<144 + eB + xcB, 256, 0, stream>>>(
            fgn_w1, fgn_b1, root1, fgn_w2, fgn_b2, root2,
            Wf1, Wf2, Rt1, Rt2, dst, cnt, x, x16, N, E, eB);

        // CSR by dst (scan_top folded into scan_final)
        scan_partial  <<<gridP, 256, 0, stream>>>(cnt, partial, N);
        scan_final    <<<gridP, 256, 0, stream>>>(cnt, partial, cursor, rowptr, N);
        scatter_kernel<<<eB, 256, 0, stream>>>(dst, cursor, perm, E);

        const int nTiles = (E + 15) / 16;
        int edgeBlocks = (nTiles + 7) / 8;
        if (edgeBlocks > 1024) edgeBlocks = 1024;

        // ---- layer 1 ----
        edge_msg<<<edgeBlocks, 512, 0, stream>>>(x16, efeat, src, Wf1, msg, E);
        rootsum <<<rsBlocks, 256, 0, stream>>>(x, msg, rowptr, cnt, perm, Rt1, bias1, h16, N);

        // ---- layer 2 ----
        edge_msg    <<<edgeBlocks, 512, 0, stream>>>(h16, efeat, src, Wf2, msg, E);
        rootsum_pool<<<rsBlocks, 256, 0, stream>>>(h16, msg, rowptr, cnt, perm, Rt2, bias2, bsum, N);

        final_fused<<<1, 256, 0, stream>>>(bsum, rsBlocks, dense_w, dense_b, (float*)d_out);
    } else {
        float* agg1   = (float*)d_ws;
        float* agg2   = agg1 + (size_t)N * F;
        float* pooled = agg2 + (size_t)N * F;
        hipMemsetAsync(d_ws, 0, (2 * (size_t)N * F + F) * sizeof(float), stream);
        ecc_edge_slow<<<eB, 256, 0, stream>>>(x, efeat, src, dst, fgn_w1, fgn_b1, agg1, E);
        ecc_node_slow<<<nodeBlocks, 256, 0, stream>>>(x, root1, bias1, agg1, N);
        ecc_edge_slow<<<eB, 256, 0, stream>>>(agg1, efeat, src, dst, fgn_w2, fgn_b2, agg2, E);
        ecc_node_slow<<<nodeBlocks, 256, 0, stream>>>(agg1, root2, bias2, agg2, N);
        pool_kernel <<<512, 256, 0, stream>>>(agg2, pooled, N);
        final_kernel<<<1, 64, 0, stream>>>(pooled, dense_w, dense_b, (float*)d_out);
    }
}

// Round 10
// 184.551 us; speedup vs baseline: 1.0581x; 1.0581x over previous
//
#include <hip/hip_runtime.h>
#include <hip/hip_bf16.h>
#include <hip/hip_fp16.h>

#define F 32
#define S 16

typedef short v8s __attribute__((ext_vector_type(8)));
typedef _Float16 v8h __attribute__((ext_vector_type(8)));
typedef float v4f __attribute__((ext_vector_type(4)));

__device__ __forceinline__ float bf_lo(unsigned u) { return __uint_as_float(u << 16); }
__device__ __forceinline__ float bf_hi(unsigned u) { return __uint_as_float(u & 0xffff0000u); }
__device__ __forceinline__ unsigned short f2bf(float f) {
    __hip_bfloat16 h = __float2bfloat16(f);  // RNE
    return *(unsigned short*)&h;
}
__device__ __forceinline__ unsigned short f2h(float f) {
    __half h = __float2half(f);              // RNE
    return *(unsigned short*)&h;
}
__device__ __forceinline__ unsigned pack2(float a, float b) {
    __hip_bfloat162 h2 = __float22bfloat162_rn(make_float2(a, b));  // v_cvt_pk_bf16_f32
    return *(unsigned*)&h2;
}
__device__ __forceinline__ unsigned pack2h(float a, float b) {
    __half2 h2 = __floats2half2_rn(a, b);    // packed f32->f16
    return *(unsigned*)&h2;
}
static inline size_t align256(size_t b) { return (b + 255) & ~(size_t)255; }

// ---------------------------------------------------------------------------
// prep: weight repack [0,144) + dst histogram [144,144+eB) + x->f16 [rest).
// ---------------------------------------------------------------------------
__global__ __launch_bounds__(256) void prep_kernel(
    const float* __restrict__ w1, const float* __restrict__ b1, const float* __restrict__ r1,
    const float* __restrict__ w2, const float* __restrict__ b2, const float* __restrict__ r2,
    unsigned short* __restrict__ Wf1, unsigned short* __restrict__ Wf2,
    unsigned short* __restrict__ Rt1, unsigned short* __restrict__ Rt2,
    const int* __restrict__ dst, int* __restrict__ cnt,
    const float* __restrict__ x, unsigned short* __restrict__ x16,
    int N, int E, int eB)
{
    const int PER = 34 * 512 + 32 * 32;
    if (blockIdx.x < 144) {
        int tid = blockIdx.x * blockDim.x + threadIdx.x;
        if (tid >= 2 * PER) return;
        const int layer = tid / PER;
        const int rem   = tid % PER;
        const float* w = layer ? w2 : w1;
        const float* b = layer ? b2 : b1;
        const float* r = layer ? r2 : r1;
        if (rem < 34 * 512) {
            const int fi   = rem >> 9;
            const int rr   = rem & 511;
            const int lane = rr >> 3;
            const int j    = rr & 7;
            const int half = fi & 1;
            const int ck   = fi >> 1;
            const int o    = (half << 4) | (lane & 15);
            const int k    = ck * 32 + (lane >> 4) * 8 + j;
            const int s    = k >> 5, f = k & 31;
            const float v  = (s < S) ? w[s * (F * F) + f * F + o] : b[f * F + o];
            (layer ? Wf2 : Wf1)[rem] = f2h(v);   // F16
        } else {
            const int q = rem - 34 * 512;
            const int o = q >> 5, f = q & 31;
            (layer ? Rt2 : Rt1)[o * F + f] = f2bf(r[f * F + o]);
        }
    } else if (blockIdx.x < 144 + eB) {
        const int e = (blockIdx.x - 144) * blockDim.x + threadIdx.x;
        if (e < E) atomicAdd(&cnt[dst[e]], 1);
    } else {
        // x -> f16 (8 floats per thread)
        const int idx = (blockIdx.x - 144 - eB) * 256 + threadIdx.x;
        if (idx < N * 4) {
            const float4* p = (const float4*)(x + (size_t)idx * 8);
            float4 a = p[0], b = p[1];
            uint4 o;
            o.x = pack2h(a.x, a.y); o.y = pack2h(a.z, a.w);
            o.z = pack2h(b.x, b.y); o.w = pack2h(b.z, b.w);
            *(uint4*)(x16 + (size_t)idx * 8) = o;
        }
    }
}

// ---------------------------------------------------------------------------
// scan_partial: per-block sums.
// ---------------------------------------------------------------------------
__global__ __launch_bounds__(256) void scan_partial(
    const int* __restrict__ cnt, int* __restrict__ partial, int N)
{
    const int i = blockIdx.x * 256 + threadIdx.x;
    int v = (i < N) ? cnt[i] : 0;
    #pragma unroll
    for (int off = 32; off > 0; off >>= 1) v += __shfl_down(v, off, 64);
    __shared__ int wsum[4];
    const int wave = threadIdx.x >> 6, lane = threadIdx.x & 63;
    if (lane == 0) wsum[wave] = v;
    __syncthreads();
    if (threadIdx.x == 0)
        partial[blockIdx.x] = wsum[0] + wsum[1] + wsum[2] + wsum[3];
}

// ---------------------------------------------------------------------------
// scan_final: computes its own block-prefix from raw per-block sums.
// ---------------------------------------------------------------------------
__global__ __launch_bounds__(256) void scan_final(
    const int* __restrict__ cnt, const int* __restrict__ partial,
    int* __restrict__ cursor, int* __restrict__ rowptr, int N)
{
    const int tid = threadIdx.x;
    __shared__ int pacc[256];
    int pre = 0;
    for (int j = tid; j < blockIdx.x; j += 256) pre += partial[j];
    pacc[tid] = pre;
    __syncthreads();
    #pragma unroll
    for (int off = 128; off > 0; off >>= 1) {
        if (tid < off) pacc[tid] += pacc[tid + off];
        __syncthreads();
    }
    const int blockPre = pacc[0];

    const int i = blockIdx.x * 256 + tid;
    const int v0 = (i < N) ? cnt[i] : 0;
    int v = v0;
    const int wave = tid >> 6, lane = tid & 63;
    #pragma unroll
    for (int off = 1; off < 64; off <<= 1) {
        int u = __shfl_up(v, off, 64);
        if (lane >= off) v += u;
    }
    __shared__ int wsum[4];
    if (lane == 63) wsum[wave] = v;
    __syncthreads();
    int woff = 0;
    for (int ww = 0; ww < 4; ++ww) woff += (ww < wave) ? wsum[ww] : 0;
    if (i < N) {
        const int excl = blockPre + woff + (v - v0);
        cursor[i] = excl;
        rowptr[i] = excl;
    }
}

// scatter: build INVERSE permutation (edge -> dst-sorted slot). perm no
// longer needed: edge_msg writes msg directly into slot order, so rootsum
// reads msg sequentially (no gather chain on the read side).
__global__ __launch_bounds__(256) void scatter_kernel(
    const int* __restrict__ dst, int* __restrict__ cursor,
    int* __restrict__ inv, int E)
{
    int e = blockIdx.x * blockDim.x + threadIdx.x;
    if (e < E) {
        int p = atomicAdd(&cursor[dst[e]], 1);
        inv[e] = p;
    }
}

// ---------------------------------------------------------------------------
// edge_msg: F16 node rows, v_pk_mul_f16 fragments, mfma_f32_16x16x32_f16.
// Writes each message to its dst-sorted slot (scattered fire-and-forget
// stores — latency-tolerant; rootsum then streams msg sequentially).
// ---------------------------------------------------------------------------
__global__ __launch_bounds__(256) void edge_msg(
    const unsigned short* __restrict__ x16,
    const float* __restrict__ ef,
    const int* __restrict__ src,
    const int* __restrict__ inv,
    const unsigned short* __restrict__ Wf,
    unsigned short* __restrict__ msg,
    int E)
{
    __shared__ v8h Wl[34 * 64];
    const int tid  = threadIdx.x;
    const int w    = tid >> 6;
    const int lane = tid & 63;
    const int lid  = lane & 15;
    const int quad = lane >> 4;

    {
        const uint4* s = (const uint4*)Wf;
        uint4* d = (uint4*)Wl;
        #pragma unroll
        for (int i = 0; i < 9; ++i) {
            const int idx = tid + 256 * i;
            if (idx < 2176) d[idx] = s[idx];
        }
    }
    __syncthreads();

    const int nTiles = (E + 15) >> 4;
    const int stride = gridDim.x * 4;
    int tile = blockIdx.x * 4 + w;
    if (tile >= nTiles) return;

    int  slot = tile * 16 + lid;
    bool live = (slot < E);
    int  s0   = live ? slot : 0;
    int  sn   = src[s0];
    int  iv   = inv[s0];
    v8h xh = *(const v8h*)(x16 + (size_t)sn * F + quad * 8);
    const float4* efv = (const float4*)(ef + (size_t)s0 * S);
    float4 c0 = efv[0], c1 = efv[1], c2 = efv[2], c3 = efv[3];

    while (true) {
        const int nextTile = tile + stride;
        v8h nxh;
        float4 nc0, nc1, nc2, nc3;
        int niv = 0;
        bool nlive = false;
        if (nextTile < nTiles) {
            const int  ns_  = nextTile * 16 + lid;
            nlive = (ns_ < E);
            const int  ns0_ = nlive ? ns_ : 0;
            const int  nsn  = src[ns0_];
            niv = inv[ns0_];
            nxh = *(const v8h*)(x16 + (size_t)nsn * F + quad * 8);
            const float4* nefv = (const float4*)(ef + (size_t)ns0_ * S);
            nc0 = nefv[0]; nc1 = nefv[1]; nc2 = nefv[2]; nc3 = nefv[3];
        }

        const float cs[S] = {c0.x, c0.y, c0.z, c0.w, c1.x, c1.y, c1.z, c1.w,
                             c2.x, c2.y, c2.z, c2.w, c3.x, c3.y, c3.z, c3.w};

        union { v8h h8; __half2 h2[4]; } xu;
        xu.h8 = xh;

        v4f acc0 = {0.f, 0.f, 0.f, 0.f};
        v4f acc1 = {0.f, 0.f, 0.f, 0.f};

        #pragma unroll
        for (int ck = 0; ck < S; ++ck) {
            const __half2 cc = __floats2half2_rn(cs[ck], cs[ck]);
            union { v8h h8; __half2 h2[4]; } fr;
            fr.h2[0] = __hmul2(cc, xu.h2[0]);
            fr.h2[1] = __hmul2(cc, xu.h2[1]);
            fr.h2[2] = __hmul2(cc, xu.h2[2]);
            fr.h2[3] = __hmul2(cc, xu.h2[3]);
            acc0 = __builtin_amdgcn_mfma_f32_16x16x32_f16(Wl[(2 * ck) * 64 + lane],     fr.h8, acc0, 0, 0, 0);
            acc1 = __builtin_amdgcn_mfma_f32_16x16x32_f16(Wl[(2 * ck + 1) * 64 + lane], fr.h8, acc1, 0, 0, 0);
        }
        acc0 = __builtin_amdgcn_mfma_f32_16x16x32_f16(Wl[32 * 64 + lane], xu.h8, acc0, 0, 0, 0);
        acc1 = __builtin_amdgcn_mfma_f32_16x16x32_f16(Wl[33 * 64 + lane], xu.h8, acc1, 0, 0, 0);

        if (live) {
            unsigned short* mp = msg + (size_t)iv * 32;
            uint2 p0, p1;
            p0.x = pack2(acc0[0], acc0[1]);
            p0.y = pack2(acc0[2], acc0[3]);
            p1.x = pack2(acc1[0], acc1[1]);
            p1.y = pack2(acc1[2], acc1[3]);
            *(uint2*)(mp + quad * 4)      = p0;
            *(uint2*)(mp + 16 + quad * 4) = p1;
        }

        if (nextTile >= nTiles) break;
        tile = nextTile;
        slot = tile * 16 + lid;
        live = nlive;
        xh = nxh;
        iv = niv;
        c0 = nc0; c1 = nc1; c2 = nc2; c3 = nc3;
    }
}

// ---------------------------------------------------------------------------
// rootsum (layer 1): msg now in dst-sorted order -> SEQUENTIAL inner loop
// (no perm indirection). Writes h ONLY as F16.
// ---------------------------------------------------------------------------
__global__ __launch_bounds__(256) void rootsum(
    const float* __restrict__ in,
    const unsigned short* __restrict__ msg,
    const int* __restrict__ rowptr,
    const int* __restrict__ cnt,
    const unsigned short* __restrict__ Rt,
    const float* __restrict__ bias,
    unsigned short* __restrict__ h16,
    int N)
{
    __shared__ float acc[64 * 33];
    __shared__ unsigned short As[64 * F];
    const int tid  = threadIdx.x;
    const int n0   = blockIdx.x * 64;
    const int w    = tid >> 6;
    const int lane = tid & 63;
    const int lid  = lane & 15;
    const int quad = lane >> 4;

    {
        const int nl = tid >> 2;
        const int kq = tid & 3;
        int n = n0 + nl; if (n > N - 1) n = N - 1;
        const float4* xp = (const float4*)(in + (size_t)n * F + kq * 8);
        float4 v0 = xp[0], v1 = xp[1];
        uint4 pk;
        pk.x = pack2(v0.x, v0.y);
        pk.y = pack2(v0.z, v0.w);
        pk.z = pack2(v1.x, v1.y);
        pk.w = pack2(v1.z, v1.w);
        const int slot = ((nl >> 4) * 4 + kq) * 16 + (nl & 15);
        *(uint4*)(As + slot * 8) = pk;
    }

    {
        const int nl = tid >> 2;
        const int oq = tid & 3;
        const int n  = n0 + nl;
        float a[8];
        #pragma unroll
        for (int j = 0; j < 8; ++j) a[j] = 0.f;
        if (n < N) {
            const int k0 = rowptr[n];
            const int k1 = k0 + cnt[n];
            for (int k = k0; k < k1; ++k) {
                const uint4 q = *(const uint4*)(msg + (size_t)k * 32 + oq * 8);
                a[0] += bf_lo(q.x); a[1] += bf_hi(q.x);
                a[2] += bf_lo(q.y); a[3] += bf_hi(q.y);
                a[4] += bf_lo(q.z); a[5] += bf_hi(q.z);
                a[6] += bf_lo(q.w); a[7] += bf_hi(q.w);
            }
        }
        float* ap = acc + nl * 33 + oq * 8;
        #pragma unroll
        for (int j = 0; j < 8; ++j) ap[j] = a[j];
    }
    __syncthreads();

    const int jt  = w & 1;
    const int ns0 = (w >> 1) * 2;
    const v8s rf = *(const v8s*)(Rt + (size_t)(jt * 16 + lid) * F + quad * 8);
    const int o0 = jt * 16 + quad * 4;
    const float4 bs = *(const float4*)(bias + o0);

    #pragma unroll
    for (int i = 0; i < 2; ++i) {
        const int ns = ns0 + i;
        const v8s af = *(const v8s*)(As + (((ns * 4 + quad) * 16) + lid) * 8);
        v4f d = {0.f, 0.f, 0.f, 0.f};
        d = __builtin_amdgcn_mfma_f32_16x16x32_bf16(rf, af, d, 0, 0, 0);
        const int n = n0 + ns * 16 + lid;
        if (n < N) {
            const float* ap = acc + (ns * 16 + lid) * 33 + o0;
            float4 hv;
            hv.x = fmaxf(d[0] + ap[0] + bs.x, 0.f);
            hv.y = fmaxf(d[1] + ap[1] + bs.y, 0.f);
            hv.z = fmaxf(d[2] + ap[2] + bs.z, 0.f);
            hv.w = fmaxf(d[3] + ap[3] + bs.w, 0.f);
            uint2 hp;
            hp.x = pack2h(hv.x, hv.y);
            hp.y = pack2h(hv.z, hv.w);
            *(uint2*)(h16 + (size_t)n * F + o0) = hp;
        }
    }
}

// ---------------------------------------------------------------------------
// rootsum_pool (layer 2): sequential msg read; per-block pooled partials
// (no device-scope fence — R7 lesson).
// ---------------------------------------------------------------------------
__global__ __launch_bounds__(256) void rootsum_pool(
    const unsigned short* __restrict__ in16,
    const unsigned short* __restrict__ msg,
    const int* __restrict__ rowptr,
    const int* __restrict__ cnt,
    const unsigned short* __restrict__ Rt,
    const float* __restrict__ bias,
    float* __restrict__ bs,
    int N)
{
    __shared__ float acc[64 * 33];
    __shared__ unsigned short As[64 * F];
    __shared__ float poolbuf[4][16];
    const int tid  = threadIdx.x;
    const int n0   = blockIdx.x * 64;
    const int w    = tid >> 6;
    const int lane = tid & 63;
    const int lid  = lane & 15;
    const int quad = lane >> 4;

    {
        const int nl = tid >> 2;
        const int kq = tid & 3;
        int n = n0 + nl; if (n > N - 1) n = N - 1;
        const uint4 hv4 = *(const uint4*)(in16 + (size_t)n * F + kq * 8);
        const __half2* hh = (const __half2*)&hv4;
        float2 f0 = __half22float2(hh[0]);
        float2 f1 = __half22float2(hh[1]);
        float2 f2 = __half22float2(hh[2]);
        float2 f3 = __half22float2(hh[3]);
        uint4 pk;
        pk.x = pack2(f0.x, f0.y);
        pk.y = pack2(f1.x, f1.y);
        pk.z = pack2(f2.x, f2.y);
        pk.w = pack2(f3.x, f3.y);
        const int slot = ((nl >> 4) * 4 + kq) * 16 + (nl & 15);
        *(uint4*)(As + slot * 8) = pk;
    }

    {
        const int nl = tid >> 2;
        const int oq = tid & 3;
        const int n  = n0 + nl;
        float a[8];
        #pragma unroll
        for (int j = 0; j < 8; ++j) a[j] = 0.f;
        if (n < N) {
            const int k0 = rowptr[n];
            const int k1 = k0 + cnt[n];
            for (int k = k0; k < k1; ++k) {
                const uint4 q = *(const uint4*)(msg + (size_t)k * 32 + oq * 8);
                a[0] += bf_lo(q.x); a[1] += bf_hi(q.x);
                a[2] += bf_lo(q.y); a[3] += bf_hi(q.y);
                a[4] += bf_lo(q.z); a[5] += bf_hi(q.z);
                a[6] += bf_lo(q.w); a[7] += bf_hi(q.w);
            }
        }
        float* ap = acc + nl * 33 + oq * 8;
        #pragma unroll
        for (int j = 0; j < 8; ++j) ap[j] = a[j];
    }
    __syncthreads();

    const int jt  = w & 1;
    const int ns0 = (w >> 1) * 2;
    const v8s rf = *(const v8s*)(Rt + (size_t)(jt * 16 + lid) * F + quad * 8);
    const int o0 = jt * 16 + quad * 4;
    const float4 bs4 = *(const float4*)(bias + o0);

    float psum[4] = {0.f, 0.f, 0.f, 0.f};

    #pragma unroll
    for (int i = 0; i < 2; ++i) {
        const int ns = ns0 + i;
        const v8s af = *(const v8s*)(As + (((ns * 4 + quad) * 16) + lid) * 8);
        v4f d = {0.f, 0.f, 0.f, 0.f};
        d = __builtin_amdgcn_mfma_f32_16x16x32_bf16(rf, af, d, 0, 0, 0);
        const int n = n0 + ns * 16 + lid;
        if (n < N) {
            const float* ap = acc + (ns * 16 + lid) * 33 + o0;
            psum[0] += fmaxf(d[0] + ap[0] + bs4.x, 0.f);
            psum[1] += fmaxf(d[1] + ap[1] + bs4.y, 0.f);
            psum[2] += fmaxf(d[2] + ap[2] + bs4.z, 0.f);
            psum[3] += fmaxf(d[3] + ap[3] + bs4.w, 0.f);
        }
    }

    #pragma unroll
    for (int m = 1; m < 16; m <<= 1) {
        psum[0] += __shfl_xor(psum[0], m, 64);
        psum[1] += __shfl_xor(psum[1], m, 64);
        psum[2] += __shfl_xor(psum[2], m, 64);
        psum[3] += __shfl_xor(psum[3], m, 64);
    }
    if (lid == 0) {
        #pragma unroll
        for (int j = 0; j < 4; ++j) poolbuf[w][quad * 4 + j] = psum[j];
    }
    __syncthreads();
    if (tid < 32) {
        const int jt2 = tid >> 4, idx = tid & 15;
        bs[(size_t)blockIdx.x * 32 + tid] = poolbuf[jt2][idx] + poolbuf[jt2 + 2][idx];
    }
}

// ---------------------------------------------------------------------------
// final_fused: reduce per-block pooled partials + dense head in one launch.
// ---------------------------------------------------------------------------
__global__ __launch_bounds__(256) void final_fused(
    const float* __restrict__ bs, int nb,
    const float* __restrict__ dw, const float* __restrict__ db,
    float* __restrict__ out)
{
    const int ch = threadIdx.x & 31, g = threadIdx.x >> 5;  // 8 row-groups
    float s = 0.f;
    for (int b = g; b < nb; b += 8) s += bs[(size_t)b * 32 + ch];
    __shared__ float red[256];
    red[threadIdx.x] = s;
    __syncthreads();
    if (threadIdx.x < 128) red[threadIdx.x] += red[threadIdx.x + 128];
    __syncthreads();
    if (threadIdx.x < 64) red[threadIdx.x] += red[threadIdx.x + 64];
    __syncthreads();
    if (threadIdx.x < 32) red[threadIdx.x] = (red[threadIdx.x] + red[threadIdx.x + 32]) * dw[threadIdx.x];
    __syncthreads();
    if (threadIdx.x == 0) {
        float t = 0.f;
        #pragma unroll
        for (int i = 0; i < 32; ++i) t += red[i];
        out[0] = t + db[0];
    }
}

// ---------------------------------------------------------------------------
// pool/final kernels retained for the fallback path.
// ---------------------------------------------------------------------------
__global__ __launch_bounds__(256) void pool_kernel(
    const float* __restrict__ h, float* __restrict__ pooled, int N)
{
    const int c = threadIdx.x & (F - 1);
    float p = 0.0f;
    for (int n = blockIdx.x * 8 + (threadIdx.x >> 5); n < N; n += gridDim.x * 8)
        p += h[(size_t)n * F + c];
    __shared__ float red[256];
    red[threadIdx.x] = p;
    __syncthreads();
    for (int off = 128; off >= F; off >>= 1) {
        if (threadIdx.x < off) red[threadIdx.x] += red[threadIdx.x + off];
        __syncthreads();
    }
    if (threadIdx.x < F) atomicAdd(&pooled[threadIdx.x], red[threadIdx.x]);
}

__global__ void final_kernel(
    const float* __restrict__ pooled, const float* __restrict__ dw,
    const float* __restrict__ db, float* __restrict__ out)
{
    const int o = threadIdx.x;
    float v = (o < F) ? pooled[o] * dw[o] : 0.0f;
    #pragma unroll
    for (int off = 32; off > 0; off >>= 1) v += __shfl_down(v, off, 64);
    if (o == 0) out[0] = v + db[0];
}

// ---------------------------------------------------------------------------
// Last-resort fallback (tiny ws): round-1 implementation.
// ---------------------------------------------------------------------------
__global__ __launch_bounds__(256, 2) void ecc_edge_slow(
    const float* __restrict__ x, const float* __restrict__ ef,
    const int* __restrict__ src, const int* __restrict__ dst,
    const float* __restrict__ W, const float* __restrict__ B,
    float* __restrict__ agg, int E)
{
    const int tid = blockIdx.x * blockDim.x + threadIdx.x;
    const bool live = (tid < E);
    const int e = live ? tid : (E - 1);
    const int sn = src[e], dn = dst[e];
    float xr[F];
    const float4* xp = (const float4*)(x + (size_t)sn * F);
    #pragma unroll
    for (int i = 0; i < F / 4; ++i) {
        float4 v = xp[i];
        xr[4*i+0] = v.x; xr[4*i+1] = v.y; xr[4*i+2] = v.z; xr[4*i+3] = v.w;
    }
    float acc[F];
    #pragma unroll
    for (int o = 0; o < F; ++o) acc[o] = 0.0f;
    const float* erow = ef + (size_t)e * S;
    for (int s = 0; s < S; ++s) {
        const float es = erow[s];
        const float* Ws = W + s * (F * F);
        #pragma unroll
        for (int f = 0; f < F; ++f) {
            const float z = es * xr[f];
            #pragma unroll
            for (int o = 0; o < F; ++o) acc[o] = fmaf(z, Ws[f * F + o], acc[o]);
        }
    }
    #pragma unroll
    for (int f = 0; f < F; ++f) {
        const float xf = xr[f];
        #pragma unroll
        for (int o = 0; o < F; ++o) acc[o] = fmaf(xf, B[f * F + o], acc[o]);
    }
    if (live) {
        float* ap = agg + (size_t)dn * F;
        #pragma unroll
        for (int o = 0; o < F; ++o) atomicAdd(ap + o, acc[o]);
    }
}

__global__ __launch_bounds__(256) void ecc_node_slow(
    const float* __restrict__ xin, const float* __restrict__ root,
    const float* __restrict__ bias, float* __restrict__ h, int N)
{
    int t = blockIdx.x * blockDim.x + threadIdx.x;
    if (t >= N * F) return;
    const int n = t >> 5, o = t & (F - 1);
    const float* xrow = xin + (size_t)n * F;
    float v = h[t] + bias[o];
    #pragma unroll
    for (int f = 0; f < F; ++f) v = fmaf(xrow[f], root[f * F + o], v);
    h[t] = fmaxf(v, 0.0f);
}

// ---------------------------------------------------------------------------
extern "C" void kernel_launch(void* const* d_in, const int* in_sizes, int n_in,
                              void* d_out, int out_size, void* d_ws, size_t ws_size,
                              hipStream_t stream) {
    const float* x      = (const float*)d_in[0];
    const float* efeat  = (const float*)d_in[1];
    const int*   src    = (const int*)d_in[2];
    const int*   dst    = (const int*)d_in[3];
    const float* fgn_w1 = (const float*)d_in[4];
    const float* fgn_b1 = (const float*)d_in[5];
    const float* root1  = (const float*)d_in[6];
    const float* bias1  = (const float*)d_in[7];
    const float* fgn_w2 = (const float*)d_in[8];
    const float* fgn_b2 = (const float*)d_in[9];
    const float* root2  = (const float*)d_in[10];
    const float* bias2  = (const float*)d_in[11];
    const float* dense_w = (const float*)d_in[12];
    const float* dense_b = (const float*)d_in[13];

    const int N = in_sizes[0] / F;
    const int E = in_sizes[2];

    const int gridP    = (N + 255) / 256;
    const int rsBlocks = (N + 63) / 64;

    const size_t pooledB = 256;
    const size_t cntB    = align256((size_t)N * 4);
    const size_t rowB    = align256((size_t)N * 4);
    const size_t curB    = align256((size_t)N * 4);
    const size_t partB   = align256((size_t)gridP * 4);
    const size_t permB   = align256((size_t)E * 4);
    const size_t efsB    = align256((size_t)E * S * 4);
    const size_t srcsB   = align256((size_t)E * 4);
    const size_t msgB    = align256((size_t)E * 32 * 2);
    const size_t hB      = (size_t)N * F * 4;
    const size_t wfB     = align256((size_t)34 * 512 * 2);
    const size_t rtB     = align256((size_t)32 * 32 * 2);
    const size_t x16B    = align256((size_t)N * F * 2);

    const size_t offCnt  = pooledB;
    const size_t offRow  = offCnt + cntB;
    const size_t offCur  = offRow + rowB;
    const size_t offPart = offCur + curB;
    const size_t offPerm = offPart + partB;
    const size_t offEfs  = offPerm + permB;
    const size_t offSrcs = offEfs + efsB;
    const size_t offMsg  = offSrcs + srcsB;
    const size_t offH1   = offMsg + msgB;
    const size_t offH2   = offH1 + hB;
    const size_t offW1   = offH2 + hB;
    const size_t offW2   = offW1 + wfB;
    const size_t offR1   = offW2 + wfB;
    const size_t offR2   = offR1 + rtB;
    const size_t need    = offR2 + rtB;

    const int eB         = (E + 255) / 256;
    const int nodeBlocks = (N * F + 255) / 256;

    if (ws_size >= need && efsB >= 2 * x16B) {
        int* cnt     = (int*)((char*)d_ws + offCnt);
        int* rowptr  = (int*)((char*)d_ws + offRow);
        int* cursor  = (int*)((char*)d_ws + offCur);
        int* partial = (int*)((char*)d_ws + offPart);
        int* inv     = (int*)((char*)d_ws + offPerm);   // edge -> sorted slot
        unsigned short* x16 = (unsigned short*)((char*)d_ws + offEfs);
        unsigned short* h16 = (unsigned short*)((char*)d_ws + offEfs + x16B);
        unsigned short* msg = (unsigned short*)((char*)d_ws + offMsg);
        float* bsum  = (float*)((char*)d_ws + offH2);
        unsigned short* Wf1 = (unsigned short*)((char*)d_ws + offW1);
        unsigned short* Wf2 = (unsigned short*)((char*)d_ws + offW2);
        unsigned short* Rt1 = (unsigned short*)((char*)d_ws + offR1);
        unsigned short* Rt2 = (unsigned short*)((char*)d_ws + offR2);

        hipMemsetAsync(d_ws, 0, pooledB + cntB, stream);

        // weight repack + dst histogram + x->f16 in one launch
        const int xcB = (N * 4 + 255) / 256;
        prep_kernel<<<144 + eB + xcB, 256, 0, stream>>>(
            fgn_w1, fgn_b1, root1, fgn_w2, fgn_b2, root2,
            Wf1, Wf2, Rt1, Rt2, dst, cnt, x, x16, N, E, eB);

        // CSR by dst (scan_top folded into scan_final); scatter builds inv
        scan_partial  <<<gridP, 256, 0, stream>>>(cnt, partial, N);
        scan_final    <<<gridP, 256, 0, stream>>>(cnt, partial, cursor, rowptr, N);
        scatter_kernel<<<eB, 256, 0, stream>>>(dst, cursor, inv, E);

        const int nTiles = (E + 15) / 16;
        int edgeBlocks = (nTiles + 3) / 4;
        if (edgeBlocks > 1024) edgeBlocks = 1024;

        // ---- layer 1 ----
        edge_msg<<<edgeBlocks, 256, 0, stream>>>(x16, efeat, src, inv, Wf1, msg, E);
        rootsum <<<rsBlocks, 256, 0, stream>>>(x, msg, rowptr, cnt, Rt1, bias1, h16, N);

        // ---- layer 2 ----
        edge_msg    <<<edgeBlocks, 256, 0, stream>>>(h16, efeat, src, inv, Wf2, msg, E);
        rootsum_pool<<<rsBlocks, 256, 0, stream>>>(h16, msg, rowptr, cnt, Rt2, bias2, bsum, N);

        final_fused<<<1, 256, 0, stream>>>(bsum, rsBlocks, dense_w, dense_b, (float*)d_out);
    } else {
        float* agg1   = (float*)d_ws;
        float* agg2   = agg1 + (size_t)N * F;
        float* pooled = agg2 + (size_t)N * F;
        hipMemsetAsync(d_ws, 0, (2 * (size_t)N * F + F) * sizeof(float), stream);
        ecc_edge_slow<<<eB, 256, 0, stream>>>(x, efeat, src, dst, fgn_w1, fgn_b1, agg1, E);
        ecc_node_slow<<<nodeBlocks, 256, 0, stream>>>(x, root1, bias1, agg1, N);
        ecc_edge_slow<<<eB, 256, 0, stream>>>(agg1, efeat, src, dst, fgn_w2, fgn_b2, agg2, E);
        ecc_node_slow<<<nodeBlocks, 256, 0, stream>>>(agg1, root2, bias2, agg2, N);
        pool_kernel <<<512, 256, 0, stream>>>(agg2, pooled, N);
        final_kernel<<<1, 64, 0, stream>>>(pooled, dense_w, dense_b, (float*)d_out);
    }
}